// Round 9
// baseline (263.864 us; speedup 1.0000x reference)
//
#include <hip/hip_runtime.h>
#include <math.h>

#define NFRAME 96
#define NTOK   197
#define NSPAT  196
#define DIM    512
#define DH     256
#define NSAMP  256
#define KSEL   49
#define SIG    0.05f
#define MPAD   208                 // padded rows per frame
#define MTOT   (NFRAME * MPAD)     // 19968 = 156*128
#define KP3    52                  // hist_f leading dim (49 + 3 ghost)

typedef unsigned short u16;
typedef __attribute__((ext_vector_type(8))) short bf16x8;   // 8 bf16 (4 VGPRs)
typedef __attribute__((ext_vector_type(4))) float f32x4;

__device__ __forceinline__ float gelu_exact(float v) {
    return 0.5f * v * (1.0f + erff(v * 0.70710678118654752440f));
}
__device__ __forceinline__ unsigned bf16_rne(float f) {
    unsigned u = __float_as_uint(f);
    return (u + 0x7fffu + ((u >> 16) & 1u)) >> 16;
}
__device__ __forceinline__ float bf16_to_f(unsigned h) {
    return __uint_as_float(h << 16);
}

// ---------------------------------------------------------------------------
// K0: fused prep. blocks [0,512): weight transpose+split. blocks [512,...):
// LN + hi/lo split of x (one wave per padded row).
// ---------------------------------------------------------------------------
__global__ __launch_bounds__(256) void k0_prep(
    const float* __restrict__ x, const float* __restrict__ gamma,
    const float* __restrict__ beta,
    const float* __restrict__ w_in, const float* __restrict__ w1,
    u16* __restrict__ wiT_hi, u16* __restrict__ wiT_lo,
    u16* __restrict__ w1T_hi, u16* __restrict__ w1T_lo,
    u16* __restrict__ xs_hi, u16* __restrict__ xs_lo)
{
    if (blockIdx.x < 512) {
        const int n = blockIdx.x & 255, which = blockIdx.x >> 8;
        const float* w = which ? w1 : w_in;
        u16* th = which ? w1T_hi : wiT_hi;
        u16* tl = which ? w1T_lo : wiT_lo;
        for (int k = threadIdx.x; k < DIM; k += 256) {
            float v = w[(size_t)k * DH + n];
            unsigned hi = bf16_rne(v);
            unsigned lo = bf16_rne(v - bf16_to_f(hi));
            th[(size_t)n * DIM + k] = (u16)hi;
            tl[(size_t)n * DIM + k] = (u16)lo;
        }
        return;
    }
    const int row  = (blockIdx.x - 512) * 4 + (threadIdx.x >> 6);
    const int lane = threadIdx.x & 63;
    const int f = row / MPAD;
    int rr = row - f * MPAD; if (rr > NTOK - 1) rr = NTOK - 1;
    const float* xr = x + ((size_t)f * NTOK + rr) * DIM + lane * 8;
    float4 a = *(const float4*)xr, b4 = *(const float4*)(xr + 4);
    float e[8] = {a.x, a.y, a.z, a.w, b4.x, b4.y, b4.z, b4.w};
    float s = 0.f, sq = 0.f;
    #pragma unroll
    for (int j = 0; j < 8; ++j) { s += e[j]; sq += e[j] * e[j]; }
    #pragma unroll
    for (int o = 32; o > 0; o >>= 1) {
        s  += __shfl_xor(s,  o, 64);
        sq += __shfl_xor(sq, o, 64);
    }
    const float mu  = s * (1.f / 512.f);
    const float var = sq * (1.f / 512.f) - mu * mu;
    const float rs  = 1.f / sqrtf(var + 1e-5f);

    const float* gp = gamma + lane * 8;
    const float* bp = beta + lane * 8;
    float4 g0 = *(const float4*)gp, g1 = *(const float4*)(gp + 4);
    float4 b0 = *(const float4*)bp, b1 = *(const float4*)(bp + 4);
    float gg[8] = {g0.x, g0.y, g0.z, g0.w, g1.x, g1.y, g1.z, g1.w};
    float bt[8] = {b0.x, b0.y, b0.z, b0.w, b1.x, b1.y, b1.z, b1.w};

    unsigned hw[4], lw[4];
    #pragma unroll
    for (int p = 0; p < 4; ++p) {
        float s0 = rs * gg[2*p],   s1 = rs * gg[2*p+1];
        float v0 = e[2*p]   * s0 + (bt[2*p]   - mu * s0);
        float v1 = e[2*p+1] * s1 + (bt[2*p+1] - mu * s1);
        unsigned h0 = bf16_rne(v0), h1 = bf16_rne(v1);
        float l0 = v0 - bf16_to_f(h0), l1 = v1 - bf16_to_f(h1);
        hw[p] = h0 | (h1 << 16);
        lw[p] = bf16_rne(l0) | (bf16_rne(l1) << 16);
    }
    size_t off = (size_t)row * DIM + lane * 8;
    *(uint4*)(xs_hi + off) = make_uint4(hw[0], hw[1], hw[2], hw[3]);
    *(uint4*)(xs_lo + off) = make_uint4(lw[0], lw[1], lw[2], lw[3]);
}

// ---------------------------------------------------------------------------
// K1a: h = gelu(xs @ w_in), 3-term bf16-split MFMA, register-prefetch
// pipelined. Tile 128(M) x 64(N), BK=32, grid 624, XCD-swizzled.
// ---------------------------------------------------------------------------
#define LDG 40
__global__ __launch_bounds__(256, 4) void k1_gemm1(
    const u16* __restrict__ xs_hi, const u16* __restrict__ xs_lo,
    const u16* __restrict__ wiT_hi, const u16* __restrict__ wiT_lo,
    u16* __restrict__ h_hi, u16* __restrict__ h_lo)
{
    __shared__ u16 Ah[128][LDG], Al[128][LDG], Bh[64][LDG], Bl[64][LDG];
    const int t = threadIdx.x, lane = t & 63, wv = t >> 6;
    const int linear = (blockIdx.x & 7) * 78 + (blockIdx.x >> 3);
    const int Mb = linear >> 2, Nb = linear & 3;
    const int R0 = Mb * 128, N0 = Nb * 64;
    const int wm = wv >> 1, wn = wv & 1;
    const int m15 = lane & 15, q = lane >> 4;

    f32x4 acc[4][2];
    #pragma unroll
    for (int i = 0; i < 4; ++i)
        #pragma unroll
        for (int j = 0; j < 2; ++j)
            acc[i][j] = (f32x4){0.f, 0.f, 0.f, 0.f};

    const int ar = t >> 1, as = (t & 1) * 16;
    const int br = t >> 2, bs = (t & 3) * 8;
    const size_t abase = (size_t)(R0 + ar) * DIM + as;
    const size_t bbase = (size_t)(N0 + br) * DIM + bs;

    uint4 pAh0 = *(const uint4*)(xs_hi + abase);
    uint4 pAh1 = *(const uint4*)(xs_hi + abase + 8);
    uint4 pAl0 = *(const uint4*)(xs_lo + abase);
    uint4 pAl1 = *(const uint4*)(xs_lo + abase + 8);
    uint4 pBh  = *(const uint4*)(wiT_hi + bbase);
    uint4 pBl  = *(const uint4*)(wiT_lo + bbase);

    for (int k0 = 0; k0 < DIM; k0 += 32) {
        __syncthreads();
        *(uint4*)&Ah[ar][as]     = pAh0;
        *(uint4*)&Ah[ar][as + 8] = pAh1;
        *(uint4*)&Al[ar][as]     = pAl0;
        *(uint4*)&Al[ar][as + 8] = pAl1;
        *(uint4*)&Bh[br][bs]     = pBh;
        *(uint4*)&Bl[br][bs]     = pBl;
        if (k0 + 32 < DIM) {
            pAh0 = *(const uint4*)(xs_hi + abase + k0 + 32);
            pAh1 = *(const uint4*)(xs_hi + abase + k0 + 40);
            pAl0 = *(const uint4*)(xs_lo + abase + k0 + 32);
            pAl1 = *(const uint4*)(xs_lo + abase + k0 + 40);
            pBh  = *(const uint4*)(wiT_hi + bbase + k0 + 32);
            pBl  = *(const uint4*)(wiT_lo + bbase + k0 + 32);
        }
        __syncthreads();

        const int ko = q * 8;
        bf16x8 ah[4], al[4], bh[2], bl[2];
        #pragma unroll
        for (int i = 0; i < 4; ++i) {
            ah[i] = *(const bf16x8*)&Ah[wm*64 + i*16 + m15][ko];
            al[i] = *(const bf16x8*)&Al[wm*64 + i*16 + m15][ko];
        }
        #pragma unroll
        for (int i = 0; i < 2; ++i) {
            bh[i] = *(const bf16x8*)&Bh[wn*32 + i*16 + m15][ko];
            bl[i] = *(const bf16x8*)&Bl[wn*32 + i*16 + m15][ko];
        }
        #pragma unroll
        for (int mt = 0; mt < 4; ++mt)
            #pragma unroll
            for (int nt = 0; nt < 2; ++nt) {
                f32x4 c = acc[mt][nt];
                c = __builtin_amdgcn_mfma_f32_16x16x32_bf16(ah[mt], bh[nt], c, 0, 0, 0);
                c = __builtin_amdgcn_mfma_f32_16x16x32_bf16(al[mt], bh[nt], c, 0, 0, 0);
                c = __builtin_amdgcn_mfma_f32_16x16x32_bf16(ah[mt], bl[nt], c, 0, 0, 0);
                acc[mt][nt] = c;
            }
    }

    #pragma unroll
    for (int mt = 0; mt < 4; ++mt)
        #pragma unroll
        for (int nt = 0; nt < 2; ++nt)
            #pragma unroll
            for (int reg = 0; reg < 4; ++reg) {
                int r = R0 + wm*64 + mt*16 + q*4 + reg;
                int c = N0 + wn*32 + nt*16 + m15;
                float v = gelu_exact(acc[mt][nt][reg]);
                unsigned hb = bf16_rne(v);
                unsigned lb = bf16_rne(v - bf16_to_f(hb));
                size_t off = (size_t)r * DH + c;
                h_hi[off] = (u16)hb;
                h_lo[off] = (u16)lb;
            }
}

// ---------------------------------------------------------------------------
// K1b: s2 = [h|g] @ w1, partial-N score epilogue -> s_half[Nb][row].
// Tile 64(M) x 128(N-half), BK=32, grid 624, XCD-swizzled, reg-prefetch.
// ---------------------------------------------------------------------------
__global__ __launch_bounds__(256, 4) void k1_gemm2(
    const u16* __restrict__ h_hi, const u16* __restrict__ h_lo,
    const u16* __restrict__ w1T_hi, const u16* __restrict__ w1T_lo,
    const float* __restrict__ w2, float* __restrict__ s_half)
{
    __shared__ u16 Ah[64][LDG], Al[64][LDG], Bh[128][LDG], Bl[128][LDG];
    __shared__ float red[2][2][32];
    const int t = threadIdx.x, lane = t & 63, wv = t >> 6;
    const int linear = (blockIdx.x & 7) * 78 + (blockIdx.x >> 3);
    const int Mb = linear >> 1, Nb = linear & 1;
    const int R0 = Mb * 64, N0 = Nb * 128;
    const int wm = wv >> 1, wn = wv & 1;
    const int m15 = lane & 15, q = lane >> 4;

    f32x4 acc[2][4];
    #pragma unroll
    for (int i = 0; i < 2; ++i)
        #pragma unroll
        for (int j = 0; j < 4; ++j)
            acc[i][j] = (f32x4){0.f, 0.f, 0.f, 0.f};

    const int ar = t >> 2, as = (t & 3) * 8;
    const int agrow = R0 + ar;
    const size_t arow_off = (size_t)agrow * DH;
    const size_t g0_off   = (size_t)((agrow / MPAD) * MPAD) * DH;
    const int br = t >> 1, bs = (t & 1) * 16;
    const size_t bbase = (size_t)(N0 + br) * DIM + bs;

    auto asrc = [&](int k0) -> size_t {
        return (k0 < DH) ? (arow_off + k0 + as) : (g0_off + (k0 - DH) + as);
    };

    uint4 pAh = *(const uint4*)(h_hi + asrc(0));
    uint4 pAl = *(const uint4*)(h_lo + asrc(0));
    uint4 pBh0 = *(const uint4*)(w1T_hi + bbase);
    uint4 pBh1 = *(const uint4*)(w1T_hi + bbase + 8);
    uint4 pBl0 = *(const uint4*)(w1T_lo + bbase);
    uint4 pBl1 = *(const uint4*)(w1T_lo + bbase + 8);

    for (int k0 = 0; k0 < DIM; k0 += 32) {
        __syncthreads();
        *(uint4*)&Ah[ar][as]     = pAh;
        *(uint4*)&Al[ar][as]     = pAl;
        *(uint4*)&Bh[br][bs]     = pBh0;
        *(uint4*)&Bh[br][bs + 8] = pBh1;
        *(uint4*)&Bl[br][bs]     = pBl0;
        *(uint4*)&Bl[br][bs + 8] = pBl1;
        if (k0 + 32 < DIM) {
            size_t srcn = asrc(k0 + 32);
            pAh  = *(const uint4*)(h_hi + srcn);
            pAl  = *(const uint4*)(h_lo + srcn);
            pBh0 = *(const uint4*)(w1T_hi + bbase + k0 + 32);
            pBh1 = *(const uint4*)(w1T_hi + bbase + k0 + 40);
            pBl0 = *(const uint4*)(w1T_lo + bbase + k0 + 32);
            pBl1 = *(const uint4*)(w1T_lo + bbase + k0 + 40);
        }
        __syncthreads();

        const int ko = q * 8;
        bf16x8 ah[2], al[2], bh[4], bl[4];
        #pragma unroll
        for (int i = 0; i < 2; ++i) {
            ah[i] = *(const bf16x8*)&Ah[wm*32 + i*16 + m15][ko];
            al[i] = *(const bf16x8*)&Al[wm*32 + i*16 + m15][ko];
        }
        #pragma unroll
        for (int i = 0; i < 4; ++i) {
            bh[i] = *(const bf16x8*)&Bh[wn*64 + i*16 + m15][ko];
            bl[i] = *(const bf16x8*)&Bl[wn*64 + i*16 + m15][ko];
        }
        #pragma unroll
        for (int mt = 0; mt < 2; ++mt)
            #pragma unroll
            for (int nt = 0; nt < 4; ++nt) {
                f32x4 c = acc[mt][nt];
                c = __builtin_amdgcn_mfma_f32_16x16x32_bf16(ah[mt], bh[nt], c, 0, 0, 0);
                c = __builtin_amdgcn_mfma_f32_16x16x32_bf16(al[mt], bh[nt], c, 0, 0, 0);
                c = __builtin_amdgcn_mfma_f32_16x16x32_bf16(ah[mt], bl[nt], c, 0, 0, 0);
                acc[mt][nt] = c;
            }
    }

    float w2v[4];
    #pragma unroll
    for (int nt = 0; nt < 4; ++nt) w2v[nt] = w2[N0 + wn*64 + nt*16 + m15];
    #pragma unroll
    for (int mt = 0; mt < 2; ++mt)
        #pragma unroll
        for (int reg = 0; reg < 4; ++reg) {
            float s = 0.f;
            #pragma unroll
            for (int nt = 0; nt < 4; ++nt)
                s += gelu_exact(acc[mt][nt][reg]) * w2v[nt];
            #pragma unroll
            for (int o = 1; o <= 8; o <<= 1)
                s += __shfl_xor(s, o, 64);
            if (m15 == 0)
                red[wn][wm][mt*16 + q*4 + reg] = s;
        }
    __syncthreads();
    if (t < 64) {
        int wmj = t >> 5, rl = t & 31;
        float sv = red[0][wmj][rl] + red[1][wmj][rl];
        s_half[(size_t)Nb * MTOT + R0 + t] = sv;
    }
}

// ---------------------------------------------------------------------------
// K23: fused select + output, one frame per block (96 blocks x 1024 thr).
// Phase A: 16 waves x 16 samples radix-descent top-49 -> LDS int histogram.
// Phase B: in-LDS transpose to [l][k], then einsum + cls write. The hist
// never touches HBM; einsum l-order matches prior rounds (bitwise-same out).
// ---------------------------------------------------------------------------
__global__ __launch_bounds__(1024) void k23_fused(
    const float* __restrict__ s_half, const float* __restrict__ noise,
    const float* __restrict__ x, float* __restrict__ out)
{
    const int f    = blockIdx.x;
    const int t    = threadIdx.x;
    const int lane = t & 63;
    const int wv   = t >> 6;              // 0..15

    __shared__ int   hist_i[KSEL * NSPAT];   // 38.4 KB, [k][l]
    __shared__ float hist_f[NSPAT * KP3];    // 40.8 KB, [l][k]

    for (int i = t; i < KSEL * NSPAT; i += 1024) hist_i[i] = 0;

    // per-frame scores (each wave computes its own copy; cheap)
    const float* sA = s_half;
    const float* sB = s_half + MTOT;
    float spv[4];
    #pragma unroll
    for (int j = 0; j < 4; ++j) {
        int l = lane + 64 * j;
        if (l < NSPAT) {
            size_t idx = (size_t)f * MPAD + 1 + l;
            spv[j] = tanhf(sA[idx] + sB[idx]);
        } else spv[j] = 0.f;
    }
    __syncthreads();

    const unsigned long long lmask = (1ull << lane) - 1ull;

    for (int si = 0; si < 16; ++si) {
        const int s = wv * 16 + si;
        const float* nz = noise + ((size_t)f * NSAMP + s) * NSPAT;
        unsigned key[4];
        #pragma unroll
        for (int j = 0; j < 4; ++j) {
            int l = lane + 64 * j;
            if (l < NSPAT) {
                float p = spv[j] + nz[l] * SIG;
                unsigned u = __float_as_uint(p);
                key[j] = (u & 0x80000000u) ? ~u : (u | 0x80000000u);
            } else {
                key[j] = 0u;
            }
        }

        unsigned ans = 0u;
        for (int bit = 31; bit >= 0; --bit) {
            unsigned cand = ans | (1u << bit);
            int cnt = 0;
            #pragma unroll
            for (int j = 0; j < 4; ++j)
                cnt += __popcll(__ballot(key[j] >= cand));
            if (cnt >= KSEL) ans = cand;
        }

        unsigned long long eq[4];
        int cgt = 0;
        #pragma unroll
        for (int j = 0; j < 4; ++j) {
            cgt += __popcll(__ballot(key[j] > ans));
            eq[j] = __ballot(key[j] == ans);
        }
        const int quota = KSEL - cgt;
        int eqpre[4]; { int run = 0;
            #pragma unroll
            for (int j = 0; j < 4; ++j) { eqpre[j] = run; run += __popcll(eq[j]); } }

        int pre = 0;
        #pragma unroll
        for (int j = 0; j < 4; ++j) {
            bool iseq = (key[j] == ans);
            int trk = eqpre[j] + __popcll(eq[j] & lmask);
            bool selj = (key[j] > ans) || (iseq && trk < quota);
            unsigned long long sb = __ballot(selj);
            int rk = pre + __popcll(sb & lmask);
            if (selj)
                atomicAdd(&hist_i[rk * NSPAT + lane + 64 * j], 1);
            pre += __popcll(sb);
        }
    }

    __syncthreads();

    // transpose to [l][KP3] (ghost k>=49 zeroed)
    for (int i = t; i < NSPAT * KP3; i += 1024) {
        int l = i / KP3, k = i - l * KP3;
        hist_f[i] = (k < KSEL) ? (float)hist_i[k * NSPAT + l] : 0.f;
    }
    // cls row
    if (t < DIM)
        out[(size_t)f * 50 * DIM + t] = x[(size_t)f * NTOK * DIM + t];
    __syncthreads();

    // einsum: thread = (tk = t>>7 in 0..7, tdc = t&127 float4-col)
    const int tdc = t & 127;
    const int tk  = t >> 7;               // wave-uniform -> LDS broadcast reads
    const float* xs = x + ((size_t)f * NTOK + 1) * DIM + tdc * 4;
    float4 acc[7];
    #pragma unroll
    for (int i = 0; i < 7; ++i) acc[i] = make_float4(0.f, 0.f, 0.f, 0.f);

    #pragma unroll 7
    for (int l = 0; l < NSPAT; ++l) {
        float4 v = *(const float4*)(xs + (size_t)l * DIM);
        const float* hl = &hist_f[l * KP3 + tk];
        #pragma unroll
        for (int i = 0; i < 7; ++i) {
            float w = hl[8 * i];
            acc[i].x += w * v.x; acc[i].y += w * v.y;
            acc[i].z += w * v.z; acc[i].w += w * v.w;
        }
    }

    const float inv = 1.f / 256.f;
    #pragma unroll
    for (int i = 0; i < 7; ++i) {
        int k = tk + 8 * i;
        if (k < KSEL) {
            float4 o = make_float4(acc[i].x * inv, acc[i].y * inv,
                                   acc[i].z * inv, acc[i].w * inv);
            *(float4*)&out[((size_t)f * 50 + 1 + k) * DIM + tdc * 4] = o;
        }
    }
}

// ---------------------------------------------------------------------------
extern "C" void kernel_launch(void* const* d_in, const int* in_sizes, int n_in,
                              void* d_out, int out_size, void* d_ws, size_t ws_size,
                              hipStream_t stream)
{
    const float* x     = (const float*)d_in[0];
    const float* noise = (const float*)d_in[1];
    const float* gamma = (const float*)d_in[2];
    const float* beta  = (const float*)d_in[3];
    const float* w_in  = (const float*)d_in[4];
    const float* w1    = (const float*)d_in[5];
    const float* w2    = (const float*)d_in[6];
    float* out = (float*)d_out;

    // ws layout (bytes; total ~62.6 MB)
    char* ws = (char*)d_ws;
    float* s_half  = (float*)(ws + 0);            // 2*19968*4    =   159,744
    u16*   wiT_hi  = (u16*)  (ws + 159744);       // 256*512*2    =   262,144
    u16*   wiT_lo  = (u16*)  (ws + 421888);
    u16*   w1T_hi  = (u16*)  (ws + 684032);
    u16*   w1T_lo  = (u16*)  (ws + 946176);
    u16*   h_hi    = (u16*)  (ws + 1208320);      // 19968*256*2  = 10,223,616
    u16*   h_lo    = (u16*)  (ws + 11431936);
    u16*   xs_hi   = (u16*)  (ws + 21655552);     // 19968*512*2  = 20,447,232
    u16*   xs_lo   = (u16*)  (ws + 42102784);     // end 62,550,016

    k0_prep<<<512 + MTOT / 4, 256, 0, stream>>>(x, gamma, beta, w_in, w1,
                                                wiT_hi, wiT_lo, w1T_hi, w1T_lo,
                                                xs_hi, xs_lo);
    k1_gemm1<<<(MTOT / 128) * 4, 256, 0, stream>>>(xs_hi, xs_lo, wiT_hi, wiT_lo,
                                                   h_hi, h_lo);
    k1_gemm2<<<(MTOT / 64) * 2, 256, 0, stream>>>(h_hi, h_lo, w1T_hi, w1T_lo,
                                                  w2, s_half);
    k23_fused<<<NFRAME, 1024, 0, stream>>>(s_half, noise, x, out);
}

// Round 10
// 220.991 us; speedup vs baseline: 1.1940x; 1.1940x over previous
//
#include <hip/hip_runtime.h>
#include <math.h>

#define NFRAME 96
#define NTOK   197
#define NSPAT  196
#define DIM    512
#define DH     256
#define NSAMP  256
#define KSEL   49
#define SIG    0.05f
#define MPAD   208                 // padded rows per frame
#define MTOT   (NFRAME * MPAD)     // 19968 = 156*128

typedef unsigned short u16;
typedef __attribute__((ext_vector_type(8))) short bf16x8;   // 8 bf16 (4 VGPRs)
typedef __attribute__((ext_vector_type(4))) float f32x4;

__device__ __forceinline__ float gelu_exact(float v) {
    return 0.5f * v * (1.0f + erff(v * 0.70710678118654752440f));
}
__device__ __forceinline__ unsigned bf16_rne(float f) {
    unsigned u = __float_as_uint(f);
    return (u + 0x7fffu + ((u >> 16) & 1u)) >> 16;
}
__device__ __forceinline__ float bf16_to_f(unsigned h) {
    return __uint_as_float(h << 16);
}

// ---------------------------------------------------------------------------
// K0: fused prep. blocks [0,512): weight transpose+split. blocks [512,...):
// LN + hi/lo split of x (one wave per padded row).
// ---------------------------------------------------------------------------
__global__ __launch_bounds__(256) void k0_prep(
    const float* __restrict__ x, const float* __restrict__ gamma,
    const float* __restrict__ beta,
    const float* __restrict__ w_in, const float* __restrict__ w1,
    u16* __restrict__ wiT_hi, u16* __restrict__ wiT_lo,
    u16* __restrict__ w1T_hi, u16* __restrict__ w1T_lo,
    u16* __restrict__ xs_hi, u16* __restrict__ xs_lo)
{
    if (blockIdx.x < 512) {
        const int n = blockIdx.x & 255, which = blockIdx.x >> 8;
        const float* w = which ? w1 : w_in;
        u16* th = which ? w1T_hi : wiT_hi;
        u16* tl = which ? w1T_lo : wiT_lo;
        for (int k = threadIdx.x; k < DIM; k += 256) {
            float v = w[(size_t)k * DH + n];
            unsigned hi = bf16_rne(v);
            unsigned lo = bf16_rne(v - bf16_to_f(hi));
            th[(size_t)n * DIM + k] = (u16)hi;
            tl[(size_t)n * DIM + k] = (u16)lo;
        }
        return;
    }
    const int row  = (blockIdx.x - 512) * 4 + (threadIdx.x >> 6);
    const int lane = threadIdx.x & 63;
    const int f = row / MPAD;
    int rr = row - f * MPAD; if (rr > NTOK - 1) rr = NTOK - 1;
    const float* xr = x + ((size_t)f * NTOK + rr) * DIM + lane * 8;
    float4 a = *(const float4*)xr, b4 = *(const float4*)(xr + 4);
    float e[8] = {a.x, a.y, a.z, a.w, b4.x, b4.y, b4.z, b4.w};
    float s = 0.f, sq = 0.f;
    #pragma unroll
    for (int j = 0; j < 8; ++j) { s += e[j]; sq += e[j] * e[j]; }
    #pragma unroll
    for (int o = 32; o > 0; o >>= 1) {
        s  += __shfl_xor(s,  o, 64);
        sq += __shfl_xor(sq, o, 64);
    }
    const float mu  = s * (1.f / 512.f);
    const float var = sq * (1.f / 512.f) - mu * mu;
    const float rs  = 1.f / sqrtf(var + 1e-5f);

    const float* gp = gamma + lane * 8;
    const float* bp = beta + lane * 8;
    float4 g0 = *(const float4*)gp, g1 = *(const float4*)(gp + 4);
    float4 b0 = *(const float4*)bp, b1 = *(const float4*)(bp + 4);
    float gg[8] = {g0.x, g0.y, g0.z, g0.w, g1.x, g1.y, g1.z, g1.w};
    float bt[8] = {b0.x, b0.y, b0.z, b0.w, b1.x, b1.y, b1.z, b1.w};

    unsigned hw[4], lw[4];
    #pragma unroll
    for (int p = 0; p < 4; ++p) {
        float s0 = rs * gg[2*p],   s1 = rs * gg[2*p+1];
        float v0 = e[2*p]   * s0 + (bt[2*p]   - mu * s0);
        float v1 = e[2*p+1] * s1 + (bt[2*p+1] - mu * s1);
        unsigned h0 = bf16_rne(v0), h1 = bf16_rne(v1);
        float l0 = v0 - bf16_to_f(h0), l1 = v1 - bf16_to_f(h1);
        hw[p] = h0 | (h1 << 16);
        lw[p] = bf16_rne(l0) | (bf16_rne(l1) << 16);
    }
    size_t off = (size_t)row * DIM + lane * 8;
    *(uint4*)(xs_hi + off) = make_uint4(hw[0], hw[1], hw[2], hw[3]);
    *(uint4*)(xs_lo + off) = make_uint4(lw[0], lw[1], lw[2], lw[3]);
}

// ---------------------------------------------------------------------------
// K1a: h = gelu(xs @ w_in), 3-term bf16-split MFMA, register-prefetch
// pipelined. Tile 128(M) x 64(N), BK=32, grid 624, XCD-swizzled.
// ---------------------------------------------------------------------------
#define LDG 40
__global__ __launch_bounds__(256, 4) void k1_gemm1(
    const u16* __restrict__ xs_hi, const u16* __restrict__ xs_lo,
    const u16* __restrict__ wiT_hi, const u16* __restrict__ wiT_lo,
    u16* __restrict__ h_hi, u16* __restrict__ h_lo)
{
    __shared__ u16 Ah[128][LDG], Al[128][LDG], Bh[64][LDG], Bl[64][LDG];
    const int t = threadIdx.x, lane = t & 63, wv = t >> 6;
    const int linear = (blockIdx.x & 7) * 78 + (blockIdx.x >> 3);
    const int Mb = linear >> 2, Nb = linear & 3;
    const int R0 = Mb * 128, N0 = Nb * 64;
    const int wm = wv >> 1, wn = wv & 1;
    const int m15 = lane & 15, q = lane >> 4;

    f32x4 acc[4][2];
    #pragma unroll
    for (int i = 0; i < 4; ++i)
        #pragma unroll
        for (int j = 0; j < 2; ++j)
            acc[i][j] = (f32x4){0.f, 0.f, 0.f, 0.f};

    const int ar = t >> 1, as = (t & 1) * 16;
    const int br = t >> 2, bs = (t & 3) * 8;
    const size_t abase = (size_t)(R0 + ar) * DIM + as;
    const size_t bbase = (size_t)(N0 + br) * DIM + bs;

    uint4 pAh0 = *(const uint4*)(xs_hi + abase);
    uint4 pAh1 = *(const uint4*)(xs_hi + abase + 8);
    uint4 pAl0 = *(const uint4*)(xs_lo + abase);
    uint4 pAl1 = *(const uint4*)(xs_lo + abase + 8);
    uint4 pBh  = *(const uint4*)(wiT_hi + bbase);
    uint4 pBl  = *(const uint4*)(wiT_lo + bbase);

    for (int k0 = 0; k0 < DIM; k0 += 32) {
        __syncthreads();
        *(uint4*)&Ah[ar][as]     = pAh0;
        *(uint4*)&Ah[ar][as + 8] = pAh1;
        *(uint4*)&Al[ar][as]     = pAl0;
        *(uint4*)&Al[ar][as + 8] = pAl1;
        *(uint4*)&Bh[br][bs]     = pBh;
        *(uint4*)&Bl[br][bs]     = pBl;
        if (k0 + 32 < DIM) {
            pAh0 = *(const uint4*)(xs_hi + abase + k0 + 32);
            pAh1 = *(const uint4*)(xs_hi + abase + k0 + 40);
            pAl0 = *(const uint4*)(xs_lo + abase + k0 + 32);
            pAl1 = *(const uint4*)(xs_lo + abase + k0 + 40);
            pBh  = *(const uint4*)(wiT_hi + bbase + k0 + 32);
            pBl  = *(const uint4*)(wiT_lo + bbase + k0 + 32);
        }
        __syncthreads();

        const int ko = q * 8;
        bf16x8 ah[4], al[4], bh[2], bl[2];
        #pragma unroll
        for (int i = 0; i < 4; ++i) {
            ah[i] = *(const bf16x8*)&Ah[wm*64 + i*16 + m15][ko];
            al[i] = *(const bf16x8*)&Al[wm*64 + i*16 + m15][ko];
        }
        #pragma unroll
        for (int i = 0; i < 2; ++i) {
            bh[i] = *(const bf16x8*)&Bh[wn*32 + i*16 + m15][ko];
            bl[i] = *(const bf16x8*)&Bl[wn*32 + i*16 + m15][ko];
        }
        #pragma unroll
        for (int mt = 0; mt < 4; ++mt)
            #pragma unroll
            for (int nt = 0; nt < 2; ++nt) {
                f32x4 c = acc[mt][nt];
                c = __builtin_amdgcn_mfma_f32_16x16x32_bf16(ah[mt], bh[nt], c, 0, 0, 0);
                c = __builtin_amdgcn_mfma_f32_16x16x32_bf16(al[mt], bh[nt], c, 0, 0, 0);
                c = __builtin_amdgcn_mfma_f32_16x16x32_bf16(ah[mt], bl[nt], c, 0, 0, 0);
                acc[mt][nt] = c;
            }
    }

    #pragma unroll
    for (int mt = 0; mt < 4; ++mt)
        #pragma unroll
        for (int nt = 0; nt < 2; ++nt)
            #pragma unroll
            for (int reg = 0; reg < 4; ++reg) {
                int r = R0 + wm*64 + mt*16 + q*4 + reg;
                int c = N0 + wn*32 + nt*16 + m15;
                float v = gelu_exact(acc[mt][nt][reg]);
                unsigned hb = bf16_rne(v);
                unsigned lb = bf16_rne(v - bf16_to_f(hb));
                size_t off = (size_t)r * DH + c;
                h_hi[off] = (u16)hb;
                h_lo[off] = (u16)lb;
            }
}

// ---------------------------------------------------------------------------
// K1b: s2 = [h|g] @ w1, partial-N score epilogue -> s_half[Nb][row].
// Tile 64(M) x 128(N-half), BK=32, grid 624, XCD-swizzled, reg-prefetch.
// ---------------------------------------------------------------------------
__global__ __launch_bounds__(256, 4) void k1_gemm2(
    const u16* __restrict__ h_hi, const u16* __restrict__ h_lo,
    const u16* __restrict__ w1T_hi, const u16* __restrict__ w1T_lo,
    const float* __restrict__ w2, float* __restrict__ s_half)
{
    __shared__ u16 Ah[64][LDG], Al[64][LDG], Bh[128][LDG], Bl[128][LDG];
    __shared__ float red[2][2][32];
    const int t = threadIdx.x, lane = t & 63, wv = t >> 6;
    const int linear = (blockIdx.x & 7) * 78 + (blockIdx.x >> 3);
    const int Mb = linear >> 1, Nb = linear & 1;
    const int R0 = Mb * 64, N0 = Nb * 128;
    const int wm = wv >> 1, wn = wv & 1;
    const int m15 = lane & 15, q = lane >> 4;

    f32x4 acc[2][4];
    #pragma unroll
    for (int i = 0; i < 2; ++i)
        #pragma unroll
        for (int j = 0; j < 4; ++j)
            acc[i][j] = (f32x4){0.f, 0.f, 0.f, 0.f};

    const int ar = t >> 2, as = (t & 3) * 8;
    const int agrow = R0 + ar;
    const size_t arow_off = (size_t)agrow * DH;
    const size_t g0_off   = (size_t)((agrow / MPAD) * MPAD) * DH;
    const int br = t >> 1, bs = (t & 1) * 16;
    const size_t bbase = (size_t)(N0 + br) * DIM + bs;

    auto asrc = [&](int k0) -> size_t {
        return (k0 < DH) ? (arow_off + k0 + as) : (g0_off + (k0 - DH) + as);
    };

    uint4 pAh = *(const uint4*)(h_hi + asrc(0));
    uint4 pAl = *(const uint4*)(h_lo + asrc(0));
    uint4 pBh0 = *(const uint4*)(w1T_hi + bbase);
    uint4 pBh1 = *(const uint4*)(w1T_hi + bbase + 8);
    uint4 pBl0 = *(const uint4*)(w1T_lo + bbase);
    uint4 pBl1 = *(const uint4*)(w1T_lo + bbase + 8);

    for (int k0 = 0; k0 < DIM; k0 += 32) {
        __syncthreads();
        *(uint4*)&Ah[ar][as]     = pAh;
        *(uint4*)&Al[ar][as]     = pAl;
        *(uint4*)&Bh[br][bs]     = pBh0;
        *(uint4*)&Bh[br][bs + 8] = pBh1;
        *(uint4*)&Bl[br][bs]     = pBl0;
        *(uint4*)&Bl[br][bs + 8] = pBl1;
        if (k0 + 32 < DIM) {
            size_t srcn = asrc(k0 + 32);
            pAh  = *(const uint4*)(h_hi + srcn);
            pAl  = *(const uint4*)(h_lo + srcn);
            pBh0 = *(const uint4*)(w1T_hi + bbase + k0 + 32);
            pBh1 = *(const uint4*)(w1T_hi + bbase + k0 + 40);
            pBl0 = *(const uint4*)(w1T_lo + bbase + k0 + 32);
            pBl1 = *(const uint4*)(w1T_lo + bbase + k0 + 40);
        }
        __syncthreads();

        const int ko = q * 8;
        bf16x8 ah[2], al[2], bh[4], bl[4];
        #pragma unroll
        for (int i = 0; i < 2; ++i) {
            ah[i] = *(const bf16x8*)&Ah[wm*32 + i*16 + m15][ko];
            al[i] = *(const bf16x8*)&Al[wm*32 + i*16 + m15][ko];
        }
        #pragma unroll
        for (int i = 0; i < 4; ++i) {
            bh[i] = *(const bf16x8*)&Bh[wn*64 + i*16 + m15][ko];
            bl[i] = *(const bf16x8*)&Bl[wn*64 + i*16 + m15][ko];
        }
        #pragma unroll
        for (int mt = 0; mt < 2; ++mt)
            #pragma unroll
            for (int nt = 0; nt < 4; ++nt) {
                f32x4 c = acc[mt][nt];
                c = __builtin_amdgcn_mfma_f32_16x16x32_bf16(ah[mt], bh[nt], c, 0, 0, 0);
                c = __builtin_amdgcn_mfma_f32_16x16x32_bf16(al[mt], bh[nt], c, 0, 0, 0);
                c = __builtin_amdgcn_mfma_f32_16x16x32_bf16(ah[mt], bl[nt], c, 0, 0, 0);
                acc[mt][nt] = c;
            }
    }

    float w2v[4];
    #pragma unroll
    for (int nt = 0; nt < 4; ++nt) w2v[nt] = w2[N0 + wn*64 + nt*16 + m15];
    #pragma unroll
    for (int mt = 0; mt < 2; ++mt)
        #pragma unroll
        for (int reg = 0; reg < 4; ++reg) {
            float s = 0.f;
            #pragma unroll
            for (int nt = 0; nt < 4; ++nt)
                s += gelu_exact(acc[mt][nt][reg]) * w2v[nt];
            #pragma unroll
            for (int o = 1; o <= 8; o <<= 1)
                s += __shfl_xor(s, o, 64);
            if (m15 == 0)
                red[wn][wm][mt*16 + q*4 + reg] = s;
        }
    __syncthreads();
    if (t < 64) {
        int wmj = t >> 5, rl = t & 31;
        float sv = red[0][wmj][rl] + red[1][wmj][rl];
        s_half[(size_t)Nb * MTOT + R0 + t] = sv;
    }
}

// ---------------------------------------------------------------------------
// K2: top-49 radix descent, LDS histogram; score = tanh(sA+sB) inline.
// grid = 192, block = 1024 (16 waves, 8 samples/wave).
// ---------------------------------------------------------------------------
__global__ __launch_bounds__(1024) void k2_select(
    const float* __restrict__ s_half, const float* __restrict__ noise,
    int* __restrict__ hist2)
{
    const int fb   = blockIdx.x;
    const int f    = fb >> 1;
    const int half = fb & 1;
    const int t    = threadIdx.x;
    const int lane = t & 63;
    const int wv   = t >> 6;

    __shared__ int hist_s[KSEL * NSPAT];  // 38.4 KB
    for (int i = t; i < KSEL * NSPAT; i += 1024) hist_s[i] = 0;

    const float* sA = s_half;
    const float* sB = s_half + MTOT;
    float spv[4];
    #pragma unroll
    for (int j = 0; j < 4; ++j) {
        int l = lane + 64 * j;
        if (l < NSPAT) {
            size_t idx = (size_t)f * MPAD + 1 + l;
            spv[j] = tanhf(sA[idx] + sB[idx]);
        } else spv[j] = 0.f;
    }
    __syncthreads();

    const unsigned long long lmask = (1ull << lane) - 1ull;

    for (int si = 0; si < 8; ++si) {
        const int s = half * 128 + wv * 8 + si;
        const float* nz = noise + ((size_t)f * NSAMP + s) * NSPAT;
        unsigned key[4];
        #pragma unroll
        for (int j = 0; j < 4; ++j) {
            int l = lane + 64 * j;
            if (l < NSPAT) {
                float p = spv[j] + nz[l] * SIG;
                unsigned u = __float_as_uint(p);
                key[j] = (u & 0x80000000u) ? ~u : (u | 0x80000000u);
            } else {
                key[j] = 0u;
            }
        }

        unsigned ans = 0u;
        for (int bit = 31; bit >= 0; --bit) {
            unsigned cand = ans | (1u << bit);
            int cnt = 0;
            #pragma unroll
            for (int j = 0; j < 4; ++j)
                cnt += __popcll(__ballot(key[j] >= cand));
            if (cnt >= KSEL) ans = cand;
        }

        unsigned long long eq[4];
        int cgt = 0;
        #pragma unroll
        for (int j = 0; j < 4; ++j) {
            cgt += __popcll(__ballot(key[j] > ans));
            eq[j] = __ballot(key[j] == ans);
        }
        const int quota = KSEL - cgt;
        int eqpre[4]; { int run = 0;
            #pragma unroll
            for (int j = 0; j < 4; ++j) { eqpre[j] = run; run += __popcll(eq[j]); } }

        int pre = 0;
        #pragma unroll
        for (int j = 0; j < 4; ++j) {
            bool iseq = (key[j] == ans);
            int trk = eqpre[j] + __popcll(eq[j] & lmask);
            bool selj = (key[j] > ans) || (iseq && trk < quota);
            unsigned long long sb = __ballot(selj);
            int rk = pre + __popcll(sb & lmask);
            if (selj)
                atomicAdd(&hist_s[rk * NSPAT + lane + 64 * j], 1);
            pre += __popcll(sb);
        }
    }

    __syncthreads();
    int* hb = hist2 + (size_t)fb * (KSEL * NSPAT);
    for (int i = t; i < KSEL * NSPAT; i += 1024)
        hb[i] = hist_s[i];
}

// ---------------------------------------------------------------------------
// K3: out = [cls | (hist/256) @ spat]. Disjoint d x8 split (no atomics):
// grid = 96 x 8 = 768 blocks, 64 cols/block, full 196-l loop with 7
// independent loads in flight. LDS hist [l][k] padded to 52; inner-loop
// weight read is one ds_read_b128 (4 consecutive k's). Bitwise-identical
// l-sum order to round 8.
// ---------------------------------------------------------------------------
#define KP3 52
__global__ __launch_bounds__(256) void k3_output(
    const float* __restrict__ x, const int* __restrict__ hist2,
    float* __restrict__ out)
{
    const int b   = blockIdx.x >> 3;
    const int ds  = blockIdx.x & 7;
    const int d0  = ds * 64;
    const int t   = threadIdx.x;
    const int tdc = t & 15;           // 16 float4 column groups (64 cols)
    const int tk  = t >> 4;           // 16 k-groups; k = tk*4 + i

    __shared__ float hist_s[NSPAT * KP3 + 16];   // 40.9 KB, [l][k] (+ghost tail)

    const int* h0 = hist2 + (size_t)(2 * b) * (KSEL * NSPAT);
    const int* h1 = h0 + KSEL * NSPAT;
    for (int i = t; i < KSEL * NSPAT; i += 256) {
        int k = i / NSPAT;
        int l = i - k * NSPAT;
        hist_s[l * KP3 + k] = (float)(h0[i] + h1[i]);
    }
    for (int i = t; i < NSPAT * 3 + 16; i += 256) {   // ghost k = 49..51 + tail
        int l = i / 3, j = i - l * 3;
        int idx = (i < NSPAT * 3) ? (l * KP3 + KSEL + j) : (NSPAT * KP3 + i - NSPAT * 3);
        hist_s[idx] = 0.f;
    }
    if (t < 64)
        out[(size_t)b * 50 * DIM + d0 + t] = x[(size_t)b * NTOK * DIM + d0 + t];
    __syncthreads();

    const float* xs = x + ((size_t)b * NTOK + 1) * DIM + d0 + tdc * 4;
    float4 acc[4];
    #pragma unroll
    for (int i = 0; i < 4; ++i) acc[i] = make_float4(0.f, 0.f, 0.f, 0.f);

    #pragma unroll 7
    for (int l = 0; l < NSPAT; ++l) {
        float4 v  = *(const float4*)(xs + (size_t)l * DIM);
        float4 w4 = *(const float4*)&hist_s[l * KP3 + tk * 4];   // 1x ds_read_b128
        acc[0].x += w4.x * v.x; acc[0].y += w4.x * v.y;
        acc[0].z += w4.x * v.z; acc[0].w += w4.x * v.w;
        acc[1].x += w4.y * v.x; acc[1].y += w4.y * v.y;
        acc[1].z += w4.y * v.z; acc[1].w += w4.y * v.w;
        acc[2].x += w4.z * v.x; acc[2].y += w4.z * v.y;
        acc[2].z += w4.z * v.z; acc[2].w += w4.z * v.w;
        acc[3].x += w4.w * v.x; acc[3].y += w4.w * v.y;
        acc[3].z += w4.w * v.z; acc[3].w += w4.w * v.w;
    }

    const float inv = 1.f / 256.f;
    #pragma unroll
    for (int i = 0; i < 4; ++i) {
        int k = tk * 4 + i;
        if (k < KSEL) {
            float4 o = make_float4(acc[i].x * inv, acc[i].y * inv,
                                   acc[i].z * inv, acc[i].w * inv);
            *(float4*)&out[((size_t)b * 50 + 1 + k) * DIM + d0 + tdc * 4] = o;
        }
    }
}

// ---------------------------------------------------------------------------
extern "C" void kernel_launch(void* const* d_in, const int* in_sizes, int n_in,
                              void* d_out, int out_size, void* d_ws, size_t ws_size,
                              hipStream_t stream)
{
    const float* x     = (const float*)d_in[0];
    const float* noise = (const float*)d_in[1];
    const float* gamma = (const float*)d_in[2];
    const float* beta  = (const float*)d_in[3];
    const float* w_in  = (const float*)d_in[4];
    const float* w1    = (const float*)d_in[5];
    const float* w2    = (const float*)d_in[6];
    float* out = (float*)d_out;

    // ws layout (bytes; total ~66.7 MB)
    char* ws = (char*)d_ws;
    int*   hist2   = (int*)  (ws + 0);            // 192*49*196*4 = 7,375,872
    float* s_half  = (float*)(ws + 7375872);      // 2*19968*4    =   159,744
    u16*   wiT_hi  = (u16*)  (ws + 7535616);      // 256*512*2    =   262,144
    u16*   wiT_lo  = (u16*)  (ws + 7797760);
    u16*   w1T_hi  = (u16*)  (ws + 8059904);
    u16*   w1T_lo  = (u16*)  (ws + 8322048);
    u16*   h_hi    = (u16*)  (ws + 8584192);      // 19968*256*2  = 10,223,616
    u16*   h_lo    = (u16*)  (ws + 18807808);
    u16*   xs_hi   = (u16*)  (ws + 29031424);     // 19968*512*2  = 20,447,232
    u16*   xs_lo   = (u16*)  (ws + 49478656);     // end 69,925,888

    k0_prep<<<512 + MTOT / 4, 256, 0, stream>>>(x, gamma, beta, w_in, w1,
                                                wiT_hi, wiT_lo, w1T_hi, w1T_lo,
                                                xs_hi, xs_lo);
    k1_gemm1<<<(MTOT / 128) * 4, 256, 0, stream>>>(xs_hi, xs_lo, wiT_hi, wiT_lo,
                                                   h_hi, h_lo);
    k1_gemm2<<<(MTOT / 64) * 2, 256, 0, stream>>>(h_hi, h_lo, w1T_hi, w1T_lo,
                                                  w2, s_half);
    k2_select<<<NFRAME * 2, 1024, 0, stream>>>(s_half, noise, hist2);
    k3_output<<<NFRAME * 8, 256, 0, stream>>>(x, hist2, out);
}

// Round 11
// 216.288 us; speedup vs baseline: 1.2200x; 1.0217x over previous
//
#include <hip/hip_runtime.h>
#include <math.h>

#define NFRAME 96
#define NTOK   197
#define NSPAT  196
#define DIM    512
#define DH     256
#define NSAMP  256
#define KSEL   49
#define SIG    0.05f
#define MPAD   208                 // padded rows per frame
#define MTOT   (NFRAME * MPAD)     // 19968 = 312*64

typedef unsigned short u16;
typedef __attribute__((ext_vector_type(8))) short bf16x8;   // 8 bf16 (4 VGPRs)
typedef __attribute__((ext_vector_type(4))) float f32x4;

__device__ __forceinline__ float gelu_exact(float v) {
    return 0.5f * v * (1.0f + erff(v * 0.70710678118654752440f));
}
__device__ __forceinline__ unsigned bf16_rne(float f) {
    unsigned u = __float_as_uint(f);
    return (u + 0x7fffu + ((u >> 16) & 1u)) >> 16;
}
__device__ __forceinline__ float bf16_to_f(unsigned h) {
    return __uint_as_float(h << 16);
}

// ---------------------------------------------------------------------------
// K0: fused prep. blocks [0,512): weight transpose+split. blocks [512,...):
// LN + hi/lo split of x (one wave per padded row).
// ---------------------------------------------------------------------------
__global__ __launch_bounds__(256) void k0_prep(
    const float* __restrict__ x, const float* __restrict__ gamma,
    const float* __restrict__ beta,
    const float* __restrict__ w_in, const float* __restrict__ w1,
    u16* __restrict__ wiT_hi, u16* __restrict__ wiT_lo,
    u16* __restrict__ w1T_hi, u16* __restrict__ w1T_lo,
    u16* __restrict__ xs_hi, u16* __restrict__ xs_lo)
{
    if (blockIdx.x < 512) {
        const int n = blockIdx.x & 255, which = blockIdx.x >> 8;
        const float* w = which ? w1 : w_in;
        u16* th = which ? w1T_hi : wiT_hi;
        u16* tl = which ? w1T_lo : wiT_lo;
        for (int k = threadIdx.x; k < DIM; k += 256) {
            float v = w[(size_t)k * DH + n];
            unsigned hi = bf16_rne(v);
            unsigned lo = bf16_rne(v - bf16_to_f(hi));
            th[(size_t)n * DIM + k] = (u16)hi;
            tl[(size_t)n * DIM + k] = (u16)lo;
        }
        return;
    }
    const int row  = (blockIdx.x - 512) * 4 + (threadIdx.x >> 6);
    const int lane = threadIdx.x & 63;
    const int f = row / MPAD;
    int rr = row - f * MPAD; if (rr > NTOK - 1) rr = NTOK - 1;
    const float* xr = x + ((size_t)f * NTOK + rr) * DIM + lane * 8;
    float4 a = *(const float4*)xr, b4 = *(const float4*)(xr + 4);
    float e[8] = {a.x, a.y, a.z, a.w, b4.x, b4.y, b4.z, b4.w};
    float s = 0.f, sq = 0.f;
    #pragma unroll
    for (int j = 0; j < 8; ++j) { s += e[j]; sq += e[j] * e[j]; }
    #pragma unroll
    for (int o = 32; o > 0; o >>= 1) {
        s  += __shfl_xor(s,  o, 64);
        sq += __shfl_xor(sq, o, 64);
    }
    const float mu  = s * (1.f / 512.f);
    const float var = sq * (1.f / 512.f) - mu * mu;
    const float rs  = 1.f / sqrtf(var + 1e-5f);

    const float* gp = gamma + lane * 8;
    const float* bp = beta + lane * 8;
    float4 g0 = *(const float4*)gp, g1 = *(const float4*)(gp + 4);
    float4 b0 = *(const float4*)bp, b1 = *(const float4*)(bp + 4);
    float gg[8] = {g0.x, g0.y, g0.z, g0.w, g1.x, g1.y, g1.z, g1.w};
    float bt[8] = {b0.x, b0.y, b0.z, b0.w, b1.x, b1.y, b1.z, b1.w};

    unsigned hw[4], lw[4];
    #pragma unroll
    for (int p = 0; p < 4; ++p) {
        float s0 = rs * gg[2*p],   s1 = rs * gg[2*p+1];
        float v0 = e[2*p]   * s0 + (bt[2*p]   - mu * s0);
        float v1 = e[2*p+1] * s1 + (bt[2*p+1] - mu * s1);
        unsigned h0 = bf16_rne(v0), h1 = bf16_rne(v1);
        float l0 = v0 - bf16_to_f(h0), l1 = v1 - bf16_to_f(h1);
        hw[p] = h0 | (h1 << 16);
        lw[p] = bf16_rne(l0) | (bf16_rne(l1) << 16);
    }
    size_t off = (size_t)row * DIM + lane * 8;
    *(uint4*)(xs_hi + off) = make_uint4(hw[0], hw[1], hw[2], hw[3]);
    *(uint4*)(xs_lo + off) = make_uint4(lw[0], lw[1], lw[2], lw[3]);
}

// ---------------------------------------------------------------------------
// K1a: h = gelu(xs @ w_in), 3-term bf16-split MFMA, register-prefetch.
// Tile 64x64, BK=32, grid = 312*4 = 1248 (4.9 blocks/CU -> fully resident),
// 4 waves of 32x32. LDS 20.5 KB, launch_bounds(256,5) -> ~20 waves/CU.
// ---------------------------------------------------------------------------
#define LDG 40
__global__ __launch_bounds__(256, 5) void k1_gemm1(
    const u16* __restrict__ xs_hi, const u16* __restrict__ xs_lo,
    const u16* __restrict__ wiT_hi, const u16* __restrict__ wiT_lo,
    u16* __restrict__ h_hi, u16* __restrict__ h_lo)
{
    __shared__ u16 Ah[64][LDG], Al[64][LDG], Bh[64][LDG], Bl[64][LDG];
    const int t = threadIdx.x, lane = t & 63, wv = t >> 6;
    // XCD swizzle: 1248 = 8 x 156; consecutive 'linear' share an XCD so the
    // 4 N-blocks of one M-tile hit that XCD's L2 with the same A-slice.
    const int linear = (blockIdx.x & 7) * 156 + (blockIdx.x >> 3);
    const int Mb = linear >> 2, Nb = linear & 3;
    const int R0 = Mb * 64, N0 = Nb * 64;
    const int wm = wv >> 1, wn = wv & 1;           // 32x32 quadrant per wave
    const int m15 = lane & 15, q = lane >> 4;

    f32x4 acc[2][2];
    #pragma unroll
    for (int i = 0; i < 2; ++i)
        #pragma unroll
        for (int j = 0; j < 2; ++j)
            acc[i][j] = (f32x4){0.f, 0.f, 0.f, 0.f};

    const int ar = t >> 2, as = (t & 3) * 8;       // 4 thr/row, 8 u16 each
    const size_t abase = (size_t)(R0 + ar) * DIM + as;
    const size_t bbase = (size_t)(N0 + ar) * DIM + as;

    uint4 pAh = *(const uint4*)(xs_hi + abase);
    uint4 pAl = *(const uint4*)(xs_lo + abase);
    uint4 pBh = *(const uint4*)(wiT_hi + bbase);
    uint4 pBl = *(const uint4*)(wiT_lo + bbase);

    for (int k0 = 0; k0 < DIM; k0 += 32) {
        __syncthreads();
        *(uint4*)&Ah[ar][as] = pAh;
        *(uint4*)&Al[ar][as] = pAl;
        *(uint4*)&Bh[ar][as] = pBh;
        *(uint4*)&Bl[ar][as] = pBl;
        if (k0 + 32 < DIM) {   // issue next tile's loads; consumed next iter
            pAh = *(const uint4*)(xs_hi + abase + k0 + 32);
            pAl = *(const uint4*)(xs_lo + abase + k0 + 32);
            pBh = *(const uint4*)(wiT_hi + bbase + k0 + 32);
            pBl = *(const uint4*)(wiT_lo + bbase + k0 + 32);
        }
        __syncthreads();

        const int ko = q * 8;
        bf16x8 ah[2], al[2], bh[2], bl[2];
        #pragma unroll
        for (int i = 0; i < 2; ++i) {
            ah[i] = *(const bf16x8*)&Ah[wm*32 + i*16 + m15][ko];
            al[i] = *(const bf16x8*)&Al[wm*32 + i*16 + m15][ko];
            bh[i] = *(const bf16x8*)&Bh[wn*32 + i*16 + m15][ko];
            bl[i] = *(const bf16x8*)&Bl[wn*32 + i*16 + m15][ko];
        }
        #pragma unroll
        for (int mt = 0; mt < 2; ++mt)
            #pragma unroll
            for (int nt = 0; nt < 2; ++nt) {
                f32x4 c = acc[mt][nt];
                c = __builtin_amdgcn_mfma_f32_16x16x32_bf16(ah[mt], bh[nt], c, 0, 0, 0);
                c = __builtin_amdgcn_mfma_f32_16x16x32_bf16(al[mt], bh[nt], c, 0, 0, 0);
                c = __builtin_amdgcn_mfma_f32_16x16x32_bf16(ah[mt], bl[nt], c, 0, 0, 0);
                acc[mt][nt] = c;
            }
    }

    #pragma unroll
    for (int mt = 0; mt < 2; ++mt)
        #pragma unroll
        for (int nt = 0; nt < 2; ++nt)
            #pragma unroll
            for (int reg = 0; reg < 4; ++reg) {
                int r = R0 + wm*32 + mt*16 + q*4 + reg;
                int c = N0 + wn*32 + nt*16 + m15;
                float v = gelu_exact(acc[mt][nt][reg]);
                unsigned hb = bf16_rne(v);
                unsigned lb = bf16_rne(v - bf16_to_f(hb));
                size_t off = (size_t)r * DH + c;
                h_hi[off] = (u16)hb;
                h_lo[off] = (u16)lb;
            }
}

// ---------------------------------------------------------------------------
// K1b: s2 = [h|g] @ w1, quarter-N score epilogue -> s_quar[Nb][row].
// Tile 64x64, BK=32, grid 1248, XCD-swizzled, reg-prefetch. k2 finishes
// with tanh(s0+s1+s2+s3).
// ---------------------------------------------------------------------------
__global__ __launch_bounds__(256, 5) void k1_gemm2(
    const u16* __restrict__ h_hi, const u16* __restrict__ h_lo,
    const u16* __restrict__ w1T_hi, const u16* __restrict__ w1T_lo,
    const float* __restrict__ w2, float* __restrict__ s_quar)
{
    __shared__ u16 Ah[64][LDG], Al[64][LDG], Bh[64][LDG], Bl[64][LDG];
    __shared__ float red[2][2][32];
    const int t = threadIdx.x, lane = t & 63, wv = t >> 6;
    const int linear = (blockIdx.x & 7) * 156 + (blockIdx.x >> 3);
    const int Mb = linear >> 2, Nb = linear & 3;
    const int R0 = Mb * 64, N0 = Nb * 64;
    const int wm = wv >> 1, wn = wv & 1;
    const int m15 = lane & 15, q = lane >> 4;

    f32x4 acc[2][2];
    #pragma unroll
    for (int i = 0; i < 2; ++i)
        #pragma unroll
        for (int j = 0; j < 2; ++j)
            acc[i][j] = (f32x4){0.f, 0.f, 0.f, 0.f};

    const int ar = t >> 2, as = (t & 3) * 8;
    const int agrow = R0 + ar;
    const size_t arow_off = (size_t)agrow * DH;
    const size_t g0_off   = (size_t)((agrow / MPAD) * MPAD) * DH;  // frame row-0 h
    const size_t bbase = (size_t)(N0 + ar) * DIM + as;

    auto asrc = [&](int k0) -> size_t {
        return (k0 < DH) ? (arow_off + k0 + as) : (g0_off + (k0 - DH) + as);
    };

    uint4 pAh = *(const uint4*)(h_hi + asrc(0));
    uint4 pAl = *(const uint4*)(h_lo + asrc(0));
    uint4 pBh = *(const uint4*)(w1T_hi + bbase);
    uint4 pBl = *(const uint4*)(w1T_lo + bbase);

    for (int k0 = 0; k0 < DIM; k0 += 32) {
        __syncthreads();
        *(uint4*)&Ah[ar][as] = pAh;
        *(uint4*)&Al[ar][as] = pAl;
        *(uint4*)&Bh[ar][as] = pBh;
        *(uint4*)&Bl[ar][as] = pBl;
        if (k0 + 32 < DIM) {
            size_t srcn = asrc(k0 + 32);
            pAh = *(const uint4*)(h_hi + srcn);
            pAl = *(const uint4*)(h_lo + srcn);
            pBh = *(const uint4*)(w1T_hi + bbase + k0 + 32);
            pBl = *(const uint4*)(w1T_lo + bbase + k0 + 32);
        }
        __syncthreads();

        const int ko = q * 8;
        bf16x8 ah[2], al[2], bh[2], bl[2];
        #pragma unroll
        for (int i = 0; i < 2; ++i) {
            ah[i] = *(const bf16x8*)&Ah[wm*32 + i*16 + m15][ko];
            al[i] = *(const bf16x8*)&Al[wm*32 + i*16 + m15][ko];
            bh[i] = *(const bf16x8*)&Bh[wn*32 + i*16 + m15][ko];
            bl[i] = *(const bf16x8*)&Bl[wn*32 + i*16 + m15][ko];
        }
        #pragma unroll
        for (int mt = 0; mt < 2; ++mt)
            #pragma unroll
            for (int nt = 0; nt < 2; ++nt) {
                f32x4 c = acc[mt][nt];
                c = __builtin_amdgcn_mfma_f32_16x16x32_bf16(ah[mt], bh[nt], c, 0, 0, 0);
                c = __builtin_amdgcn_mfma_f32_16x16x32_bf16(al[mt], bh[nt], c, 0, 0, 0);
                c = __builtin_amdgcn_mfma_f32_16x16x32_bf16(ah[mt], bl[nt], c, 0, 0, 0);
                acc[mt][nt] = c;
            }
    }

    // quarter-N epilogue: gelu -> .w2 -> reduce over this block's 64 cols
    float w2v[2];
    #pragma unroll
    for (int nt = 0; nt < 2; ++nt) w2v[nt] = w2[N0 + wn*32 + nt*16 + m15];
    #pragma unroll
    for (int mt = 0; mt < 2; ++mt)
        #pragma unroll
        for (int reg = 0; reg < 4; ++reg) {
            float s = gelu_exact(acc[mt][0][reg]) * w2v[0] +
                      gelu_exact(acc[mt][1][reg]) * w2v[1];
            #pragma unroll
            for (int o = 1; o <= 8; o <<= 1)
                s += __shfl_xor(s, o, 64);
            if (m15 == 0)
                red[wn][wm][mt*16 + q*4 + reg] = s;
        }
    __syncthreads();
    if (t < 64) {
        int wmj = t >> 5, rl = t & 31;
        float sv = red[0][wmj][rl] + red[1][wmj][rl];
        s_quar[(size_t)Nb * MTOT + R0 + t] = sv;
    }
}

// ---------------------------------------------------------------------------
// K2: top-49 radix descent, LDS histogram; score = tanh(s0+s1+s2+s3).
// grid = 192, block = 1024 (16 waves, 8 samples/wave).
// ---------------------------------------------------------------------------
__global__ __launch_bounds__(1024) void k2_select(
    const float* __restrict__ s_quar, const float* __restrict__ noise,
    int* __restrict__ hist2)
{
    const int fb   = blockIdx.x;
    const int f    = fb >> 1;
    const int half = fb & 1;
    const int t    = threadIdx.x;
    const int lane = t & 63;
    const int wv   = t >> 6;

    __shared__ int hist_s[KSEL * NSPAT];  // 38.4 KB
    for (int i = t; i < KSEL * NSPAT; i += 1024) hist_s[i] = 0;

    const float* s0 = s_quar;
    const float* s1 = s_quar + MTOT;
    const float* s2 = s_quar + 2 * (size_t)MTOT;
    const float* s3 = s_quar + 3 * (size_t)MTOT;
    float spv[4];
    #pragma unroll
    for (int j = 0; j < 4; ++j) {
        int l = lane + 64 * j;
        if (l < NSPAT) {
            size_t idx = (size_t)f * MPAD + 1 + l;
            spv[j] = tanhf(s0[idx] + s1[idx] + s2[idx] + s3[idx]);
        } else spv[j] = 0.f;
    }
    __syncthreads();

    const unsigned long long lmask = (1ull << lane) - 1ull;

    for (int si = 0; si < 8; ++si) {
        const int s = half * 128 + wv * 8 + si;
        const float* nz = noise + ((size_t)f * NSAMP + s) * NSPAT;
        unsigned key[4];
        #pragma unroll
        for (int j = 0; j < 4; ++j) {
            int l = lane + 64 * j;
            if (l < NSPAT) {
                float p = spv[j] + nz[l] * SIG;
                unsigned u = __float_as_uint(p);
                key[j] = (u & 0x80000000u) ? ~u : (u | 0x80000000u);
            } else {
                key[j] = 0u;
            }
        }

        unsigned ans = 0u;
        for (int bit = 31; bit >= 0; --bit) {
            unsigned cand = ans | (1u << bit);
            int cnt = 0;
            #pragma unroll
            for (int j = 0; j < 4; ++j)
                cnt += __popcll(__ballot(key[j] >= cand));
            if (cnt >= KSEL) ans = cand;
        }

        unsigned long long eq[4];
        int cgt = 0;
        #pragma unroll
        for (int j = 0; j < 4; ++j) {
            cgt += __popcll(__ballot(key[j] > ans));
            eq[j] = __ballot(key[j] == ans);
        }
        const int quota = KSEL - cgt;
        int eqpre[4]; { int run = 0;
            #pragma unroll
            for (int j = 0; j < 4; ++j) { eqpre[j] = run; run += __popcll(eq[j]); } }

        int pre = 0;
        #pragma unroll
        for (int j = 0; j < 4; ++j) {
            bool iseq = (key[j] == ans);
            int trk = eqpre[j] + __popcll(eq[j] & lmask);
            bool selj = (key[j] > ans) || (iseq && trk < quota);
            unsigned long long sb = __ballot(selj);
            int rk = pre + __popcll(sb & lmask);
            if (selj)
                atomicAdd(&hist_s[rk * NSPAT + lane + 64 * j], 1);
            pre += __popcll(sb);
        }
    }

    __syncthreads();
    int* hb = hist2 + (size_t)fb * (KSEL * NSPAT);
    for (int i = t; i < KSEL * NSPAT; i += 1024)
        hb[i] = hist_s[i];
}

// ---------------------------------------------------------------------------
// K3: out = [cls | (hist/256) @ spat]. Disjoint d x8 split (no atomics):
// grid = 96 x 8 = 768 blocks, 64 cols/block, full 196-l loop with 7
// independent loads in flight. LDS hist [l][k] padded to 52; inner-loop
// weight read is one ds_read_b128.
// ---------------------------------------------------------------------------
#define KP3 52
__global__ __launch_bounds__(256) void k3_output(
    const float* __restrict__ x, const int* __restrict__ hist2,
    float* __restrict__ out)
{
    const int b   = blockIdx.x >> 3;
    const int ds  = blockIdx.x & 7;
    const int d0  = ds * 64;
    const int t   = threadIdx.x;
    const int tdc = t & 15;           // 16 float4 column groups (64 cols)
    const int tk  = t >> 4;           // 16 k-groups; k = tk*4 + i

    __shared__ float hist_s[NSPAT * KP3 + 16];   // 40.9 KB, [l][k] (+ghost tail)

    const int* h0 = hist2 + (size_t)(2 * b) * (KSEL * NSPAT);
    const int* h1 = h0 + KSEL * NSPAT;
    for (int i = t; i < KSEL * NSPAT; i += 256) {
        int k = i / NSPAT;
        int l = i - k * NSPAT;
        hist_s[l * KP3 + k] = (float)(h0[i] + h1[i]);
    }
    for (int i = t; i < NSPAT * 3 + 16; i += 256) {   // ghost k = 49..51 + tail
        int l = i / 3, j = i - l * 3;
        int idx = (i < NSPAT * 3) ? (l * KP3 + KSEL + j) : (NSPAT * KP3 + i - NSPAT * 3);
        hist_s[idx] = 0.f;
    }
    if (t < 64)
        out[(size_t)b * 50 * DIM + d0 + t] = x[(size_t)b * NTOK * DIM + d0 + t];
    __syncthreads();

    const float* xs = x + ((size_t)b * NTOK + 1) * DIM + d0 + tdc * 4;
    float4 acc[4];
    #pragma unroll
    for (int i = 0; i < 4; ++i) acc[i] = make_float4(0.f, 0.f, 0.f, 0.f);

    #pragma unroll 7
    for (int l = 0; l < NSPAT; ++l) {
        float4 v  = *(const float4*)(xs + (size_t)l * DIM);
        float4 w4 = *(const float4*)&hist_s[l * KP3 + tk * 4];   // 1x ds_read_b128
        acc[0].x += w4.x * v.x; acc[0].y += w4.x * v.y;
        acc[0].z += w4.x * v.z; acc[0].w += w4.x * v.w;
        acc[1].x += w4.y * v.x; acc[1].y += w4.y * v.y;
        acc[1].z += w4.y * v.z; acc[1].w += w4.y * v.w;
        acc[2].x += w4.z * v.x; acc[2].y += w4.z * v.y;
        acc[2].z += w4.z * v.z; acc[2].w += w4.z * v.w;
        acc[3].x += w4.w * v.x; acc[3].y += w4.w * v.y;
        acc[3].z += w4.w * v.z; acc[3].w += w4.w * v.w;
    }

    const float inv = 1.f / 256.f;
    #pragma unroll
    for (int i = 0; i < 4; ++i) {
        int k = tk * 4 + i;
        if (k < KSEL) {
            float4 o = make_float4(acc[i].x * inv, acc[i].y * inv,
                                   acc[i].z * inv, acc[i].w * inv);
            *(float4*)&out[((size_t)b * 50 + 1 + k) * DIM + d0 + tdc * 4] = o;
        }
    }
}

// ---------------------------------------------------------------------------
extern "C" void kernel_launch(void* const* d_in, const int* in_sizes, int n_in,
                              void* d_out, int out_size, void* d_ws, size_t ws_size,
                              hipStream_t stream)
{
    const float* x     = (const float*)d_in[0];
    const float* noise = (const float*)d_in[1];
    const float* gamma = (const float*)d_in[2];
    const float* beta  = (const float*)d_in[3];
    const float* w_in  = (const float*)d_in[4];
    const float* w1    = (const float*)d_in[5];
    const float* w2    = (const float*)d_in[6];
    float* out = (float*)d_out;

    // ws layout (bytes; total ~70.1 MB)
    char* ws = (char*)d_ws;
    int*   hist2   = (int*)  (ws + 0);            // 192*49*196*4 = 7,375,872
    float* s_quar  = (float*)(ws + 7375872);      // 4*19968*4    =   319,488
    u16*   wiT_hi  = (u16*)  (ws + 7695360);      // 256*512*2    =   262,144
    u16*   wiT_lo  = (u16*)  (ws + 7957504);
    u16*   w1T_hi  = (u16*)  (ws + 8219648);
    u16*   w1T_lo  = (u16*)  (ws + 8481792);
    u16*   h_hi    = (u16*)  (ws + 8743936);      // 19968*256*2  = 10,223,616
    u16*   h_lo    = (u16*)  (ws + 18967552);
    u16*   xs_hi   = (u16*)  (ws + 29191168);     // 19968*512*2  = 20,447,232
    u16*   xs_lo   = (u16*)  (ws + 49638400);     // end 70,085,632

    k0_prep<<<512 + MTOT / 4, 256, 0, stream>>>(x, gamma, beta, w_in, w1,
                                                wiT_hi, wiT_lo, w1T_hi, w1T_lo,
                                                xs_hi, xs_lo);
    k1_gemm1<<<(MTOT / 64) * 4, 256, 0, stream>>>(xs_hi, xs_lo, wiT_hi, wiT_lo,
                                                  h_hi, h_lo);
    k1_gemm2<<<(MTOT / 64) * 4, 256, 0, stream>>>(h_hi, h_lo, w1T_hi, w1T_lo,
                                                  w2, s_quar);
    k2_select<<<NFRAME * 2, 1024, 0, stream>>>(s_quar, noise, hist2);
    k3_output<<<NFRAME * 8, 256, 0, stream>>>(x, hist2, out);
}

// Round 12
// 214.921 us; speedup vs baseline: 1.2277x; 1.0064x over previous
//
#include <hip/hip_runtime.h>
#include <math.h>

#define NFRAME 96
#define NTOK   197
#define NSPAT  196
#define DIM    512
#define DH     256
#define NSAMP  256
#define KSEL   49
#define SIG    0.05f
#define MPAD   208                 // padded rows per frame
#define MTOT   (NFRAME * MPAD)     // 19968 = 312*64

typedef unsigned short u16;
typedef __attribute__((ext_vector_type(8))) short bf16x8;   // 8 bf16 (4 VGPRs)
typedef __attribute__((ext_vector_type(4))) float f32x4;

__device__ __forceinline__ float gelu_exact(float v) {
    return 0.5f * v * (1.0f + erff(v * 0.70710678118654752440f));
}
__device__ __forceinline__ unsigned bf16_rne(float f) {
    unsigned u = __float_as_uint(f);
    return (u + 0x7fffu + ((u >> 16) & 1u)) >> 16;
}
__device__ __forceinline__ float bf16_to_f(unsigned h) {
    return __uint_as_float(h << 16);
}

// ---------------------------------------------------------------------------
// K0: fused prep. blocks [0,512): weight transpose+split. blocks [512,...):
// LN + hi/lo split of x (one wave per padded row).
// ---------------------------------------------------------------------------
__global__ __launch_bounds__(256) void k0_prep(
    const float* __restrict__ x, const float* __restrict__ gamma,
    const float* __restrict__ beta,
    const float* __restrict__ w_in, const float* __restrict__ w1,
    u16* __restrict__ wiT_hi, u16* __restrict__ wiT_lo,
    u16* __restrict__ w1T_hi, u16* __restrict__ w1T_lo,
    u16* __restrict__ xs_hi, u16* __restrict__ xs_lo)
{
    if (blockIdx.x < 512) {
        const int n = blockIdx.x & 255, which = blockIdx.x >> 8;
        const float* w = which ? w1 : w_in;
        u16* th = which ? w1T_hi : wiT_hi;
        u16* tl = which ? w1T_lo : wiT_lo;
        for (int k = threadIdx.x; k < DIM; k += 256) {
            float v = w[(size_t)k * DH + n];
            unsigned hi = bf16_rne(v);
            unsigned lo = bf16_rne(v - bf16_to_f(hi));
            th[(size_t)n * DIM + k] = (u16)hi;
            tl[(size_t)n * DIM + k] = (u16)lo;
        }
        return;
    }
    const int row  = (blockIdx.x - 512) * 4 + (threadIdx.x >> 6);
    const int lane = threadIdx.x & 63;
    const int f = row / MPAD;
    int rr = row - f * MPAD; if (rr > NTOK - 1) rr = NTOK - 1;
    const float* xr = x + ((size_t)f * NTOK + rr) * DIM + lane * 8;
    float4 a = *(const float4*)xr, b4 = *(const float4*)(xr + 4);
    float e[8] = {a.x, a.y, a.z, a.w, b4.x, b4.y, b4.z, b4.w};
    float s = 0.f, sq = 0.f;
    #pragma unroll
    for (int j = 0; j < 8; ++j) { s += e[j]; sq += e[j] * e[j]; }
    #pragma unroll
    for (int o = 32; o > 0; o >>= 1) {
        s  += __shfl_xor(s,  o, 64);
        sq += __shfl_xor(sq, o, 64);
    }
    const float mu  = s * (1.f / 512.f);
    const float var = sq * (1.f / 512.f) - mu * mu;
    const float rs  = 1.f / sqrtf(var + 1e-5f);

    const float* gp = gamma + lane * 8;
    const float* bp = beta + lane * 8;
    float4 g0 = *(const float4*)gp, g1 = *(const float4*)(gp + 4);
    float4 b0 = *(const float4*)bp, b1 = *(const float4*)(bp + 4);
    float gg[8] = {g0.x, g0.y, g0.z, g0.w, g1.x, g1.y, g1.z, g1.w};
    float bt[8] = {b0.x, b0.y, b0.z, b0.w, b1.x, b1.y, b1.z, b1.w};

    unsigned hw[4], lw[4];
    #pragma unroll
    for (int p = 0; p < 4; ++p) {
        float s0 = rs * gg[2*p],   s1 = rs * gg[2*p+1];
        float v0 = e[2*p]   * s0 + (bt[2*p]   - mu * s0);
        float v1 = e[2*p+1] * s1 + (bt[2*p+1] - mu * s1);
        unsigned h0 = bf16_rne(v0), h1 = bf16_rne(v1);
        float l0 = v0 - bf16_to_f(h0), l1 = v1 - bf16_to_f(h1);
        hw[p] = h0 | (h1 << 16);
        lw[p] = bf16_rne(l0) | (bf16_rne(l1) << 16);
    }
    size_t off = (size_t)row * DIM + lane * 8;
    *(uint4*)(xs_hi + off) = make_uint4(hw[0], hw[1], hw[2], hw[3]);
    *(uint4*)(xs_lo + off) = make_uint4(lw[0], lw[1], lw[2], lw[3]);
}

// ---------------------------------------------------------------------------
// K1a: h = gelu(xs @ w_in), 3-term bf16-split MFMA, register-prefetch.
// Tile 64x64, BK=64 (8 K-iters, half the barriers of BK=32), grid 1248,
// XCD-swizzled. LDS 36.9 KB -> 4 blocks/CU. MFMA order bitwise-identical
// to the BK=32 version (kh=0 then kh=1 replays the old iteration pair).
// ---------------------------------------------------------------------------
#define LDG 72
__global__ __launch_bounds__(256, 4) void k1_gemm1(
    const u16* __restrict__ xs_hi, const u16* __restrict__ xs_lo,
    const u16* __restrict__ wiT_hi, const u16* __restrict__ wiT_lo,
    u16* __restrict__ h_hi, u16* __restrict__ h_lo)
{
    __shared__ u16 Ah[64][LDG], Al[64][LDG], Bh[64][LDG], Bl[64][LDG];
    const int t = threadIdx.x, lane = t & 63, wv = t >> 6;
    const int linear = (blockIdx.x & 7) * 156 + (blockIdx.x >> 3);
    const int Mb = linear >> 2, Nb = linear & 3;
    const int R0 = Mb * 64, N0 = Nb * 64;
    const int wm = wv >> 1, wn = wv & 1;           // 32x32 quadrant per wave
    const int m15 = lane & 15, q = lane >> 4;

    f32x4 acc[2][2];
    #pragma unroll
    for (int i = 0; i < 2; ++i)
        #pragma unroll
        for (int j = 0; j < 2; ++j)
            acc[i][j] = (f32x4){0.f, 0.f, 0.f, 0.f};

    const int ar = t >> 2, as = (t & 3) * 16;      // 4 thr/row, 16 u16 each
    const size_t abase = (size_t)(R0 + ar) * DIM + as;
    const size_t bbase = (size_t)(N0 + ar) * DIM + as;

    uint4 pAh0 = *(const uint4*)(xs_hi + abase);
    uint4 pAh1 = *(const uint4*)(xs_hi + abase + 8);
    uint4 pAl0 = *(const uint4*)(xs_lo + abase);
    uint4 pAl1 = *(const uint4*)(xs_lo + abase + 8);
    uint4 pBh0 = *(const uint4*)(wiT_hi + bbase);
    uint4 pBh1 = *(const uint4*)(wiT_hi + bbase + 8);
    uint4 pBl0 = *(const uint4*)(wiT_lo + bbase);
    uint4 pBl1 = *(const uint4*)(wiT_lo + bbase + 8);

    for (int k0 = 0; k0 < DIM; k0 += 64) {
        __syncthreads();
        *(uint4*)&Ah[ar][as]     = pAh0;
        *(uint4*)&Ah[ar][as + 8] = pAh1;
        *(uint4*)&Al[ar][as]     = pAl0;
        *(uint4*)&Al[ar][as + 8] = pAl1;
        *(uint4*)&Bh[ar][as]     = pBh0;
        *(uint4*)&Bh[ar][as + 8] = pBh1;
        *(uint4*)&Bl[ar][as]     = pBl0;
        *(uint4*)&Bl[ar][as + 8] = pBl1;
        if (k0 + 64 < DIM) {   // issue next tile's loads; consumed next iter
            pAh0 = *(const uint4*)(xs_hi + abase + k0 + 64);
            pAh1 = *(const uint4*)(xs_hi + abase + k0 + 72);
            pAl0 = *(const uint4*)(xs_lo + abase + k0 + 64);
            pAl1 = *(const uint4*)(xs_lo + abase + k0 + 72);
            pBh0 = *(const uint4*)(wiT_hi + bbase + k0 + 64);
            pBh1 = *(const uint4*)(wiT_hi + bbase + k0 + 72);
            pBl0 = *(const uint4*)(wiT_lo + bbase + k0 + 64);
            pBl1 = *(const uint4*)(wiT_lo + bbase + k0 + 72);
        }
        __syncthreads();

        #pragma unroll
        for (int kh = 0; kh < 2; ++kh) {
            const int ko = kh * 32 + q * 8;
            bf16x8 ah[2], al[2], bh[2], bl[2];
            #pragma unroll
            for (int i = 0; i < 2; ++i) {
                ah[i] = *(const bf16x8*)&Ah[wm*32 + i*16 + m15][ko];
                al[i] = *(const bf16x8*)&Al[wm*32 + i*16 + m15][ko];
                bh[i] = *(const bf16x8*)&Bh[wn*32 + i*16 + m15][ko];
                bl[i] = *(const bf16x8*)&Bl[wn*32 + i*16 + m15][ko];
            }
            #pragma unroll
            for (int mt = 0; mt < 2; ++mt)
                #pragma unroll
                for (int nt = 0; nt < 2; ++nt) {
                    f32x4 c = acc[mt][nt];
                    c = __builtin_amdgcn_mfma_f32_16x16x32_bf16(ah[mt], bh[nt], c, 0, 0, 0);
                    c = __builtin_amdgcn_mfma_f32_16x16x32_bf16(al[mt], bh[nt], c, 0, 0, 0);
                    c = __builtin_amdgcn_mfma_f32_16x16x32_bf16(ah[mt], bl[nt], c, 0, 0, 0);
                    acc[mt][nt] = c;
                }
        }
    }

    #pragma unroll
    for (int mt = 0; mt < 2; ++mt)
        #pragma unroll
        for (int nt = 0; nt < 2; ++nt)
            #pragma unroll
            for (int reg = 0; reg < 4; ++reg) {
                int r = R0 + wm*32 + mt*16 + q*4 + reg;
                int c = N0 + wn*32 + nt*16 + m15;
                float v = gelu_exact(acc[mt][nt][reg]);
                unsigned hb = bf16_rne(v);
                unsigned lb = bf16_rne(v - bf16_to_f(hb));
                size_t off = (size_t)r * DH + c;
                h_hi[off] = (u16)hb;
                h_lo[off] = (u16)lb;
            }
}

// ---------------------------------------------------------------------------
// K1b: s2 = [h|g] @ w1, quarter-N score epilogue -> s_quar[Nb][row].
// Tile 64x64, BK=64, grid 1248, XCD-swizzled, reg-prefetch. k2 finishes
// with tanh(s0+s1+s2+s3). The DH=256 h|g boundary is 64-aligned, so each
// BK=64 chunk is entirely h or entirely g.
// ---------------------------------------------------------------------------
__global__ __launch_bounds__(256, 4) void k1_gemm2(
    const u16* __restrict__ h_hi, const u16* __restrict__ h_lo,
    const u16* __restrict__ w1T_hi, const u16* __restrict__ w1T_lo,
    const float* __restrict__ w2, float* __restrict__ s_quar)
{
    __shared__ u16 Ah[64][LDG], Al[64][LDG], Bh[64][LDG], Bl[64][LDG];
    __shared__ float red[2][2][32];
    const int t = threadIdx.x, lane = t & 63, wv = t >> 6;
    const int linear = (blockIdx.x & 7) * 156 + (blockIdx.x >> 3);
    const int Mb = linear >> 2, Nb = linear & 3;
    const int R0 = Mb * 64, N0 = Nb * 64;
    const int wm = wv >> 1, wn = wv & 1;
    const int m15 = lane & 15, q = lane >> 4;

    f32x4 acc[2][2];
    #pragma unroll
    for (int i = 0; i < 2; ++i)
        #pragma unroll
        for (int j = 0; j < 2; ++j)
            acc[i][j] = (f32x4){0.f, 0.f, 0.f, 0.f};

    const int ar = t >> 2, as = (t & 3) * 16;
    const int agrow = R0 + ar;
    const size_t arow_off = (size_t)agrow * DH;
    const size_t g0_off   = (size_t)((agrow / MPAD) * MPAD) * DH;  // frame row-0 h
    const size_t bbase = (size_t)(N0 + ar) * DIM + as;

    auto asrc = [&](int k0) -> size_t {
        return (k0 < DH) ? (arow_off + k0 + as) : (g0_off + (k0 - DH) + as);
    };

    uint4 pAh0 = *(const uint4*)(h_hi + asrc(0));
    uint4 pAh1 = *(const uint4*)(h_hi + asrc(0) + 8);
    uint4 pAl0 = *(const uint4*)(h_lo + asrc(0));
    uint4 pAl1 = *(const uint4*)(h_lo + asrc(0) + 8);
    uint4 pBh0 = *(const uint4*)(w1T_hi + bbase);
    uint4 pBh1 = *(const uint4*)(w1T_hi + bbase + 8);
    uint4 pBl0 = *(const uint4*)(w1T_lo + bbase);
    uint4 pBl1 = *(const uint4*)(w1T_lo + bbase + 8);

    for (int k0 = 0; k0 < DIM; k0 += 64) {
        __syncthreads();
        *(uint4*)&Ah[ar][as]     = pAh0;
        *(uint4*)&Ah[ar][as + 8] = pAh1;
        *(uint4*)&Al[ar][as]     = pAl0;
        *(uint4*)&Al[ar][as + 8] = pAl1;
        *(uint4*)&Bh[ar][as]     = pBh0;
        *(uint4*)&Bh[ar][as + 8] = pBh1;
        *(uint4*)&Bl[ar][as]     = pBl0;
        *(uint4*)&Bl[ar][as + 8] = pBl1;
        if (k0 + 64 < DIM) {
            size_t srcn = asrc(k0 + 64);
            pAh0 = *(const uint4*)(h_hi + srcn);
            pAh1 = *(const uint4*)(h_hi + srcn + 8);
            pAl0 = *(const uint4*)(h_lo + srcn);
            pAl1 = *(const uint4*)(h_lo + srcn + 8);
            pBh0 = *(const uint4*)(w1T_hi + bbase + k0 + 64);
            pBh1 = *(const uint4*)(w1T_hi + bbase + k0 + 72);
            pBl0 = *(const uint4*)(w1T_lo + bbase + k0 + 64);
            pBl1 = *(const uint4*)(w1T_lo + bbase + k0 + 72);
        }
        __syncthreads();

        #pragma unroll
        for (int kh = 0; kh < 2; ++kh) {
            const int ko = kh * 32 + q * 8;
            bf16x8 ah[2], al[2], bh[2], bl[2];
            #pragma unroll
            for (int i = 0; i < 2; ++i) {
                ah[i] = *(const bf16x8*)&Ah[wm*32 + i*16 + m15][ko];
                al[i] = *(const bf16x8*)&Al[wm*32 + i*16 + m15][ko];
                bh[i] = *(const bf16x8*)&Bh[wn*32 + i*16 + m15][ko];
                bl[i] = *(const bf16x8*)&Bl[wn*32 + i*16 + m15][ko];
            }
            #pragma unroll
            for (int mt = 0; mt < 2; ++mt)
                #pragma unroll
                for (int nt = 0; nt < 2; ++nt) {
                    f32x4 c = acc[mt][nt];
                    c = __builtin_amdgcn_mfma_f32_16x16x32_bf16(ah[mt], bh[nt], c, 0, 0, 0);
                    c = __builtin_amdgcn_mfma_f32_16x16x32_bf16(al[mt], bh[nt], c, 0, 0, 0);
                    c = __builtin_amdgcn_mfma_f32_16x16x32_bf16(ah[mt], bl[nt], c, 0, 0, 0);
                    acc[mt][nt] = c;
                }
        }
    }

    // quarter-N epilogue: gelu -> .w2 -> reduce over this block's 64 cols
    float w2v[2];
    #pragma unroll
    for (int nt = 0; nt < 2; ++nt) w2v[nt] = w2[N0 + wn*32 + nt*16 + m15];
    #pragma unroll
    for (int mt = 0; mt < 2; ++mt)
        #pragma unroll
        for (int reg = 0; reg < 4; ++reg) {
            float s = gelu_exact(acc[mt][0][reg]) * w2v[0] +
                      gelu_exact(acc[mt][1][reg]) * w2v[1];
            #pragma unroll
            for (int o = 1; o <= 8; o <<= 1)
                s += __shfl_xor(s, o, 64);
            if (m15 == 0)
                red[wn][wm][mt*16 + q*4 + reg] = s;
        }
    __syncthreads();
    if (t < 64) {
        int wmj = t >> 5, rl = t & 31;
        float sv = red[0][wmj][rl] + red[1][wmj][rl];
        s_quar[(size_t)Nb * MTOT + R0 + t] = sv;
    }
}

// ---------------------------------------------------------------------------
// K2: top-49 radix descent, LDS histogram; score = tanh(s0+s1+s2+s3).
// grid = 192, block = 1024 (16 waves, 8 samples/wave).
// ---------------------------------------------------------------------------
__global__ __launch_bounds__(1024) void k2_select(
    const float* __restrict__ s_quar, const float* __restrict__ noise,
    int* __restrict__ hist2)
{
    const int fb   = blockIdx.x;
    const int f    = fb >> 1;
    const int half = fb & 1;
    const int t    = threadIdx.x;
    const int lane = t & 63;
    const int wv   = t >> 6;

    __shared__ int hist_s[KSEL * NSPAT];  // 38.4 KB
    for (int i = t; i < KSEL * NSPAT; i += 1024) hist_s[i] = 0;

    const float* s0 = s_quar;
    const float* s1 = s_quar + MTOT;
    const float* s2 = s_quar + 2 * (size_t)MTOT;
    const float* s3 = s_quar + 3 * (size_t)MTOT;
    float spv[4];
    #pragma unroll
    for (int j = 0; j < 4; ++j) {
        int l = lane + 64 * j;
        if (l < NSPAT) {
            size_t idx = (size_t)f * MPAD + 1 + l;
            spv[j] = tanhf(s0[idx] + s1[idx] + s2[idx] + s3[idx]);
        } else spv[j] = 0.f;
    }
    __syncthreads();

    const unsigned long long lmask = (1ull << lane) - 1ull;

    for (int si = 0; si < 8; ++si) {
        const int s = half * 128 + wv * 8 + si;
        const float* nz = noise + ((size_t)f * NSAMP + s) * NSPAT;
        unsigned key[4];
        #pragma unroll
        for (int j = 0; j < 4; ++j) {
            int l = lane + 64 * j;
            if (l < NSPAT) {
                float p = spv[j] + nz[l] * SIG;
                unsigned u = __float_as_uint(p);
                key[j] = (u & 0x80000000u) ? ~u : (u | 0x80000000u);
            } else {
                key[j] = 0u;
            }
        }

        unsigned ans = 0u;
        for (int bit = 31; bit >= 0; --bit) {
            unsigned cand = ans | (1u << bit);
            int cnt = 0;
            #pragma unroll
            for (int j = 0; j < 4; ++j)
                cnt += __popcll(__ballot(key[j] >= cand));
            if (cnt >= KSEL) ans = cand;
        }

        unsigned long long eq[4];
        int cgt = 0;
        #pragma unroll
        for (int j = 0; j < 4; ++j) {
            cgt += __popcll(__ballot(key[j] > ans));
            eq[j] = __ballot(key[j] == ans);
        }
        const int quota = KSEL - cgt;
        int eqpre[4]; { int run = 0;
            #pragma unroll
            for (int j = 0; j < 4; ++j) { eqpre[j] = run; run += __popcll(eq[j]); } }

        int pre = 0;
        #pragma unroll
        for (int j = 0; j < 4; ++j) {
            bool iseq = (key[j] == ans);
            int trk = eqpre[j] + __popcll(eq[j] & lmask);
            bool selj = (key[j] > ans) || (iseq && trk < quota);
            unsigned long long sb = __ballot(selj);
            int rk = pre + __popcll(sb & lmask);
            if (selj)
                atomicAdd(&hist_s[rk * NSPAT + lane + 64 * j], 1);
            pre += __popcll(sb);
        }
    }

    __syncthreads();
    int* hb = hist2 + (size_t)fb * (KSEL * NSPAT);
    for (int i = t; i < KSEL * NSPAT; i += 1024)
        hb[i] = hist_s[i];
}

// ---------------------------------------------------------------------------
// K3: out = [cls | (hist/256) @ spat]. Disjoint d x8 split (no atomics):
// grid = 96 x 8 = 768 blocks, 64 cols/block, full 196-l loop with 7
// independent loads in flight. LDS hist [l][k] padded to 52; inner-loop
// weight read is one ds_read_b128.
// ---------------------------------------------------------------------------
#define KP3 52
__global__ __launch_bounds__(256) void k3_output(
    const float* __restrict__ x, const int* __restrict__ hist2,
    float* __restrict__ out)
{
    const int b   = blockIdx.x >> 3;
    const int ds  = blockIdx.x & 7;
    const int d0  = ds * 64;
    const int t   = threadIdx.x;
    const int tdc = t & 15;           // 16 float4 column groups (64 cols)
    const int tk  = t >> 4;           // 16 k-groups; k = tk*4 + i

    __shared__ float hist_s[NSPAT * KP3 + 16];   // 40.9 KB, [l][k] (+ghost tail)

    const int* h0 = hist2 + (size_t)(2 * b) * (KSEL * NSPAT);
    const int* h1 = h0 + KSEL * NSPAT;
    for (int i = t; i < KSEL * NSPAT; i += 256) {
        int k = i / NSPAT;
        int l = i - k * NSPAT;
        hist_s[l * KP3 + k] = (float)(h0[i] + h1[i]);
    }
    for (int i = t; i < NSPAT * 3 + 16; i += 256) {   // ghost k = 49..51 + tail
        int l = i / 3, j = i - l * 3;
        int idx = (i < NSPAT * 3) ? (l * KP3 + KSEL + j) : (NSPAT * KP3 + i - NSPAT * 3);
        hist_s[idx] = 0.f;
    }
    if (t < 64)
        out[(size_t)b * 50 * DIM + d0 + t] = x[(size_t)b * NTOK * DIM + d0 + t];
    __syncthreads();

    const float* xs = x + ((size_t)b * NTOK + 1) * DIM + d0 + tdc * 4;
    float4 acc[4];
    #pragma unroll
    for (int i = 0; i < 4; ++i) acc[i] = make_float4(0.f, 0.f, 0.f, 0.f);

    #pragma unroll 7
    for (int l = 0; l < NSPAT; ++l) {
        float4 v  = *(const float4*)(xs + (size_t)l * DIM);
        float4 w4 = *(const float4*)&hist_s[l * KP3 + tk * 4];   // 1x ds_read_b128
        acc[0].x += w4.x * v.x; acc[0].y += w4.x * v.y;
        acc[0].z += w4.x * v.z; acc[0].w += w4.x * v.w;
        acc[1].x += w4.y * v.x; acc[1].y += w4.y * v.y;
        acc[1].z += w4.y * v.z; acc[1].w += w4.y * v.w;
        acc[2].x += w4.z * v.x; acc[2].y += w4.z * v.y;
        acc[2].z += w4.z * v.z; acc[2].w += w4.z * v.w;
        acc[3].x += w4.w * v.x; acc[3].y += w4.w * v.y;
        acc[3].z += w4.w * v.z; acc[3].w += w4.w * v.w;
    }

    const float inv = 1.f / 256.f;
    #pragma unroll
    for (int i = 0; i < 4; ++i) {
        int k = tk * 4 + i;
        if (k < KSEL) {
            float4 o = make_float4(acc[i].x * inv, acc[i].y * inv,
                                   acc[i].z * inv, acc[i].w * inv);
            *(float4*)&out[((size_t)b * 50 + 1 + k) * DIM + d0 + tdc * 4] = o;
        }
    }
}

// ---------------------------------------------------------------------------
extern "C" void kernel_launch(void* const* d_in, const int* in_sizes, int n_in,
                              void* d_out, int out_size, void* d_ws, size_t ws_size,
                              hipStream_t stream)
{
    const float* x     = (const float*)d_in[0];
    const float* noise = (const float*)d_in[1];
    const float* gamma = (const float*)d_in[2];
    const float* beta  = (const float*)d_in[3];
    const float* w_in  = (const float*)d_in[4];
    const float* w1    = (const float*)d_in[5];
    const float* w2    = (const float*)d_in[6];
    float* out = (float*)d_out;

    // ws layout (bytes; total ~70.1 MB)
    char* ws = (char*)d_ws;
    int*   hist2   = (int*)  (ws + 0);            // 192*49*196*4 = 7,375,872
    float* s_quar  = (float*)(ws + 7375872);      // 4*19968*4    =   319,488
    u16*   wiT_hi  = (u16*)  (ws + 7695360);      // 256*512*2    =   262,144
    u16*   wiT_lo  = (u16*)  (ws + 7957504);
    u16*   w1T_hi  = (u16*)  (ws + 8219648);
    u16*   w1T_lo  = (u16*)  (ws + 8481792);
    u16*   h_hi    = (u16*)  (ws + 8743936);      // 19968*256*2  = 10,223,616
    u16*   h_lo    = (u16*)  (ws + 18967552);
    u16*   xs_hi   = (u16*)  (ws + 29191168);     // 19968*512*2  = 20,447,232
    u16*   xs_lo   = (u16*)  (ws + 49638400);     // end 70,085,632

    k0_prep<<<512 + MTOT / 4, 256, 0, stream>>>(x, gamma, beta, w_in, w1,
                                                wiT_hi, wiT_lo, w1T_hi, w1T_lo,
                                                xs_hi, xs_lo);
    k1_gemm1<<<(MTOT / 64) * 4, 256, 0, stream>>>(xs_hi, xs_lo, wiT_hi, wiT_lo,
                                                  h_hi, h_lo);
    k1_gemm2<<<(MTOT / 64) * 4, 256, 0, stream>>>(h_hi, h_lo, w1T_hi, w1T_lo,
                                                  w2, s_quar);
    k2_select<<<NFRAME * 2, 1024, 0, stream>>>(s_quar, noise, hist2);
    k3_output<<<NFRAME * 8, 256, 0, stream>>>(x, hist2, out);
}